// Round 10
// baseline (354.248 us; speedup 1.0000x reference)
//
#include <hip/hip_runtime.h>
#include <math.h>

#define NPTS  8192
#define BATCH 4

typedef __bf16 bf16x8 __attribute__((ext_vector_type(8)));
typedef float  f32x16 __attribute__((ext_vector_type(16)));

// min-fold with a DPP-shifted copy of v (VALU only, no DS traffic).
template<int CTRL, int RMASK>
__device__ __forceinline__ float dpp_min(float v) {
    int x = __builtin_amdgcn_update_dpp(__float_as_int(v), __float_as_int(v),
                                        CTRL, RMASK, 0xF, false);
    return fminf(v, __int_as_float(x));
}

// in-lane min over the 16 MFMA output rows (min3-friendly tree)
__device__ __forceinline__ float min16(const f32x16& c) {
    float t0 = fminf(fminf(c[0], c[1]), c[2]);
    float t1 = fminf(fminf(c[3], c[4]), c[5]);
    float t2 = fminf(fminf(c[6], c[7]), c[8]);
    float t3 = fminf(fminf(c[9], c[10]), c[11]);
    float t4 = fminf(fminf(c[12], c[13]), c[14]);
    float u0 = fminf(fminf(t0, t1), c[15]);
    float u1 = fminf(t2, t3);
    return fminf(fminf(u0, u1), t4);
}

// Grid: 1024 blocks = b(4) x ng(16) x mg(16); 256 threads = 4 waves.
// Block: 512 template rows (4 n-tiles/wave) x 512 LDS-staged source points.
// v10: REGISTER-RESIDENT main loop. All 16 B-fragments are loaded into
// registers once (16 ds_read_b128/wave, conflict-free); the nt x mt loop is
// then pure MFMA + v_min3 with zero memory ops. __launch_bounds__(256) with
// no min-wave arg -> up to 512 unified regs/wave: spill (the silent killer
// of rounds 3/6/7, and partially 2/9 per R2's 12.6MB scratch writes) is
// structurally impossible for this ~150-reg live set.
__global__ __launch_bounds__(256) void chamfer_mfma_kernel(
    const float* __restrict__ tpl, const float* __restrict__ src,
    float* __restrict__ tpart, float* __restrict__ spart)
{
    __shared__ uint4 gv0[512];        // 8 KB: khalf0 g-vecs, 16B stride (conflict-free)
    __shared__ uint4 gv1[512];        // 8 KB: khalf1 g-vecs
    __shared__ float sminW[4][512];   // 8 KB: per-wave source-side partial mins

    const int bid  = blockIdx.x;
    const int mg   = bid & 15;
    const int ng   = (bid >> 4) & 15;
    const int b    = bid >> 8;
    const int t    = threadIdx.x;
    const int lane = t & 63;
    const int wave = t >> 6;
    const int khalf = lane >> 5;   // K-half this lane supplies / C row-set it owns
    const int lr   = lane & 31;    // row (A) / col (B) within 32-tile

    const float* tb = tpl + (size_t)b * NPTS * 3;
    const float* sb = src + (size_t)b * NPTS * 3;

    // ---- stage 512 source g-vectors (B operand), 2 points per thread ----
    // khalf0 slots: [-2xh,-2xl,-2xh,-2xl | -2yh,-2yl,-2yh,-2yl]
    // khalf1 slots: [-2zh,-2zl,-2zh,-2zl |   1,   1,  nsh, nsl]
    {
        const float2* s2 = (const float2*)(sb + (size_t)mg * 512 * 3);
        float2 q0 = s2[t * 3 + 0], q1 = s2[t * 3 + 1], q2 = s2[t * 3 + 2];
        float px[2] = {q0.x, q1.y};
        float py[2] = {q0.y, q2.x};
        float pz[2] = {q1.x, q2.y};
#pragma unroll
        for (int j = 0; j < 2; ++j) {
            float x = px[j], y = py[j], z = pz[j];
            float ns = x * x + y * y + z * z;
            __bf16 xh = (__bf16)x, yh = (__bf16)y, zh = (__bf16)z;
            float xl = x - (float)xh, yl = y - (float)yh, zl = z - (float)zh;
            __bf16 nsh = (__bf16)ns; float nsl = ns - (float)nsh;
            __bf16 xh2 = (__bf16)(-2.0f * (float)xh), xl2 = (__bf16)(-2.0f * xl);
            __bf16 yh2 = (__bf16)(-2.0f * (float)yh), yl2 = (__bf16)(-2.0f * yl);
            __bf16 zh2 = (__bf16)(-2.0f * (float)zh), zl2 = (__bf16)(-2.0f * zl);
            bf16x8 g0, g1;
            g0[0] = xh2; g0[1] = xl2; g0[2] = xh2; g0[3] = xl2;
            g0[4] = yh2; g0[5] = yl2; g0[6] = yh2; g0[7] = yl2;
            g1[0] = zh2; g1[1] = zl2; g1[2] = zh2; g1[3] = zl2;
            g1[4] = (__bf16)1.0f; g1[5] = (__bf16)1.0f;
            g1[6] = nsh; g1[7] = (__bf16)nsl;
            int p = t * 2 + j;
            gv0[p] = __builtin_bit_cast(uint4, g0);
            gv1[p] = __builtin_bit_cast(uint4, g1);
        }
    }

    // ---- build A fragments (template side), 4 n-tiles per wave ----
    // khalf0 slots: [xh,xh,xl,xl | yh,yh,yl,yl]
    // khalf1 slots: [zh,zh,zl,zl | nqh,nql,1,1]
    bf16x8 afrag[4];
    const int rowbase = ng * 512 + wave * 128;
#pragma unroll
    for (int nt = 0; nt < 4; ++nt) {
        int row = rowbase + nt * 32 + lr;
        float x = tb[row * 3 + 0], y = tb[row * 3 + 1], z = tb[row * 3 + 2];
        float nq = x * x + y * y + z * z;
        __bf16 xh = (__bf16)x, yh = (__bf16)y, zh = (__bf16)z;
        float xl = x - (float)xh, yl = y - (float)yh, zl = z - (float)zh;
        __bf16 nqh = (__bf16)nq; float nql = nq - (float)nqh;
        bf16x8 f0, f1;
        f0[0] = xh; f0[1] = xh; f0[2] = (__bf16)xl; f0[3] = (__bf16)xl;
        f0[4] = yh; f0[5] = yh; f0[6] = (__bf16)yl; f0[7] = (__bf16)yl;
        f1[0] = zh; f1[1] = zh; f1[2] = (__bf16)zl; f1[3] = (__bf16)zl;
        f1[4] = nqh; f1[5] = (__bf16)nql; f1[6] = (__bf16)1.0f; f1[7] = (__bf16)1.0f;
        afrag[nt] = khalf ? f1 : f0;
    }

    __syncthreads();

    // ---- hoist ALL 16 B-fragments into registers (32 VGPRs) ----
    const uint4* gvk = khalf ? gv1 : gv0;
    bf16x8 bfrag[16];
#pragma unroll
    for (int mt = 0; mt < 16; ++mt)
        bfrag[mt] = __builtin_bit_cast(bf16x8, gvk[mt * 32 + lr]);

    f32x16 czero = {};

    float smin[16];                       // per-m-tile source mins, run across nt
#pragma unroll
    for (int r = 0; r < 16; ++r) smin[r] = 3.0e38f;

#pragma unroll
    for (int nt = 0; nt < 4; ++nt) {
        float tmin[16];
#pragma unroll
        for (int r = 0; r < 16; ++r) tmin[r] = 3.0e38f;

        // pure register main loop: 16 MFMA + min3 folds, no memory ops
#pragma unroll
        for (int mt2 = 0; mt2 < 8; ++mt2) {
            f32x16 c0 = __builtin_amdgcn_mfma_f32_32x32x16_bf16(afrag[nt], bfrag[2 * mt2], czero, 0, 0, 0);
            f32x16 c1 = __builtin_amdgcn_mfma_f32_32x32x16_bf16(afrag[nt], bfrag[2 * mt2 + 1], czero, 0, 0, 0);
            // template-side: paired fold -> v_min3_f32
#pragma unroll
            for (int r = 0; r < 16; ++r)
                tmin[r] = fminf(fminf(tmin[r], c0[r]), c1[r]);
            // source-side: in-lane tree, accumulate in registers
            smin[2 * mt2]     = fminf(smin[2 * mt2],     min16(c0));
            smin[2 * mt2 + 1] = fminf(smin[2 * mt2 + 1], min16(c1));
        }

        // ---- template-side column-min via DPP (VALU only) ----
#pragma unroll
        for (int r = 0; r < 16; ++r) {
            float v = tmin[r];
            v = dpp_min<0xB1, 0xF>(v);
            v = dpp_min<0x4E, 0xF>(v);
            v = dpp_min<0x124, 0xF>(v);
            v = dpp_min<0x128, 0xF>(v);
            v = dpp_min<0x142, 0xA>(v);
            tmin[r] = v;
        }
        if (lr == 31) {   // lanes 31 and 63
            float* tp = tpart + (((size_t)(b * 16 + ng)) * 512) * 16 + mg;
#pragma unroll
            for (int r = 0; r < 16; ++r) {
                int row_local = wave * 128 + nt * 32 + (r & 3) + 8 * (r >> 2) + 4 * khalf;
                tp[(size_t)row_local * 16] = fmaxf(tmin[r], 0.0f);
            }
        }
    }

    // ---- source-side: fold khalf halves, publish per-wave, combine ----
#pragma unroll
    for (int mt = 0; mt < 16; ++mt) {
        float v = fminf(smin[mt], __shfl_xor(smin[mt], 32));
        if (lane < 32) sminW[wave][mt * 32 + lr] = fmaxf(v, 0.0f);
    }
    __syncthreads();
    {
        // two source points per thread: min over the 4 per-wave partials
        float v0 = fminf(fminf(sminW[0][t], sminW[1][t]),
                         fminf(sminW[2][t], sminW[3][t]));
        int t2 = t + 256;
        float v1 = fminf(fminf(sminW[0][t2], sminW[1][t2]),
                         fminf(sminW[2][t2], sminW[3][t2]));
        float* sp = spart + (((size_t)(b * 16 + mg)) * 512) * 16 + ng;
        sp[(size_t)t * 16]  = v0;
        sp[(size_t)t2 * 16] = v1;
    }
}

// Pass 2: per point, min over its 16 chunk-slots (contiguous float4 reads),
// sqrt, deterministic per-block partial sums. Blocks 0-127: template points,
// 128-255: source points (block-uniform).
__global__ __launch_bounds__(256) void chamfer_reduce_kernel(
    const float* __restrict__ part, float* __restrict__ partials)
{
    int t = threadIdx.x;
    size_t p = (size_t)blockIdx.x * 256 + t;
    const float4* v4 = (const float4*)(part + p * 16);
    float4 a = v4[0], bq = v4[1], cq = v4[2], dq = v4[3];
    float t0 = fminf(fminf(a.x, a.y), a.z);
    float t1 = fminf(fminf(a.w, bq.x), bq.y);
    float t2 = fminf(fminf(bq.z, bq.w), cq.x);
    float t3 = fminf(fminf(cq.y, cq.z), cq.w);
    float t4 = fminf(fminf(dq.x, dq.y), dq.z);
    float u0 = fminf(fminf(t0, t1), dq.w);
    float u1 = fminf(t2, t3);
    float v = sqrtf(fminf(fminf(u0, u1), t4));

    for (int off = 32; off > 0; off >>= 1) v += __shfl_down(v, off);
    __shared__ float ws[4];
    int wave = t >> 6;
    if ((t & 63) == 0) ws[wave] = v;
    __syncthreads();
    if (t == 0) partials[blockIdx.x] = ws[0] + ws[1] + ws[2] + ws[3];
}

// Pass 3: deterministic final combine.
__global__ void chamfer_final_kernel(const float* __restrict__ partials,
                                     float* __restrict__ out)
{
    int t = threadIdx.x;                 // 256 threads
    float v = partials[t];
    for (int off = 32; off > 0; off >>= 1) v += __shfl_down(v, off);
    __shared__ float ws[4];
    int wave = t >> 6;
    if ((t & 63) == 0) ws[wave] = v;
    __syncthreads();
    if (t == 0) {
        float s0 = ws[0] + ws[1];   // blocks 0-127   = template side
        float s1 = ws[2] + ws[3];   // blocks 128-255 = source side
        out[0] = 0.5f * (s0 + s1) / (float)(BATCH * NPTS);
    }
}

extern "C" void kernel_launch(void* const* d_in, const int* in_sizes, int n_in,
                              void* d_out, int out_size, void* d_ws, size_t ws_size,
                              hipStream_t stream) {
    const float* tpl = (const float*)d_in[0];  // [B, N, 3] fp32
    const float* src = (const float*)d_in[1];  // [B, M, 3] fp32

    // part: [65536][16] floats = 4 MB; fully rewritten each call -> no init.
    float* part     = (float*)d_ws;
    float* tpart    = part;
    float* spart    = part + (size_t)32768 * 16;
    float* partials = part + (size_t)65536 * 16;   // 256 floats

    chamfer_mfma_kernel<<<1024, 256, 0, stream>>>(tpl, src, tpart, spart);
    chamfer_reduce_kernel<<<256, 256, 0, stream>>>(part, partials);
    chamfer_final_kernel<<<1, 256, 0, stream>>>(partials, (float*)d_out);
}

// Round 11
// 35.664 us; speedup vs baseline: 9.9330x; 9.9330x over previous
//
#include <hip/hip_runtime.h>
#include <math.h>

#define NPTS  8192
#define BATCH 4

typedef __bf16 bf16x8 __attribute__((ext_vector_type(8)));
typedef float  f32x4  __attribute__((ext_vector_type(4)));

// min-fold with a DPP-shifted copy of v (VALU only, no DS traffic).
template<int CTRL, int RMASK>
__device__ __forceinline__ float dpp_min(float v) {
    int x = __builtin_amdgcn_update_dpp(__float_as_int(v), __float_as_int(v),
                                        CTRL, RMASK, 0xF, false);
    return fminf(v, __int_as_float(x));
}

// Grid: 2048 blocks = b(4) x ng(32) x mg(16); 256 threads = 4 waves.
// Block: 256 template rows (4 n-tiles of 16 per wave) x 512 LDS-staged source
// points (32 m-tiles of 16). v11: mfma_f32_16x16x32_bf16 (4-reg accumulators)
// to escape the 32x32 shape's AGPR-half split + accvgpr-move tax that caused
// every spill/bloat from R2-R10. K-slots 0-15 carry the verified limb/norm
// packing; slots 16-31 are zeroed via a broadcast zero B-fragment for lane
// groups 2-3 (zero on one operand side suffices).
__global__ __launch_bounds__(256, 4) void chamfer_mfma_kernel(
    const float* __restrict__ tpl, const float* __restrict__ src,
    float* __restrict__ tpart, float* __restrict__ spart)
{
    __shared__ uint4 gsl[2][512];       // 16 KB: slice-major source g-vectors
    __shared__ float sminW[4][2][512];  // 16 KB: per-wave, per-khalf source mins
    __shared__ uint4 zfrag;             // 16 B: zero B-fragment (k=16..31)

    const int bid  = blockIdx.x;
    const int mg   = bid & 15;
    const int ng   = (bid >> 4) & 31;
    const int b    = bid >> 9;
    const int t    = threadIdx.x;
    const int lane = t & 63;
    const int wave = t >> 6;
    const int g    = lane >> 4;    // k-slice group 0..3 (k = g*8 .. g*8+7)
    const int col  = lane & 15;    // A-row / B-col index within a 16-tile

    if (t == 0) zfrag = make_uint4(0u, 0u, 0u, 0u);

    const float* tb = tpl + (size_t)b * NPTS * 3;
    const float* sb = src + (size_t)b * NPTS * 3;

    // ---- stage 512 source g-vectors, 2 points per thread ----
    // slice0 (k0-7):  [-2xh,-2xl,-2xh,-2xl | -2yh,-2yl,-2yh,-2yl]
    // slice1 (k8-15): [-2zh,-2zl,-2zh,-2zl |   1,   1,  nsh, nsl]
    {
        const float2* s2 = (const float2*)(sb + (size_t)mg * 512 * 3);
        float2 q0 = s2[t * 3 + 0], q1 = s2[t * 3 + 1], q2 = s2[t * 3 + 2];
        float px[2] = {q0.x, q1.y};
        float py[2] = {q0.y, q2.x};
        float pz[2] = {q1.x, q2.y};
#pragma unroll
        for (int j = 0; j < 2; ++j) {
            float x = px[j], y = py[j], z = pz[j];
            float ns = x * x + y * y + z * z;
            __bf16 xh = (__bf16)x, yh = (__bf16)y, zh = (__bf16)z;
            float xl = x - (float)xh, yl = y - (float)yh, zl = z - (float)zh;
            __bf16 nsh = (__bf16)ns; float nsl = ns - (float)nsh;
            __bf16 xh2 = (__bf16)(-2.0f * (float)xh), xl2 = (__bf16)(-2.0f * xl);
            __bf16 yh2 = (__bf16)(-2.0f * (float)yh), yl2 = (__bf16)(-2.0f * yl);
            __bf16 zh2 = (__bf16)(-2.0f * (float)zh), zl2 = (__bf16)(-2.0f * zl);
            bf16x8 g0, g1;
            g0[0] = xh2; g0[1] = xl2; g0[2] = xh2; g0[3] = xl2;
            g0[4] = yh2; g0[5] = yl2; g0[6] = yh2; g0[7] = yl2;
            g1[0] = zh2; g1[1] = zl2; g1[2] = zh2; g1[3] = zl2;
            g1[4] = (__bf16)1.0f; g1[5] = (__bf16)1.0f;
            g1[6] = nsh; g1[7] = (__bf16)nsl;
            int p = t * 2 + j;
            gsl[0][p] = __builtin_bit_cast(uint4, g0);
            gsl[1][p] = __builtin_bit_cast(uint4, g1);
        }
    }

    // ---- A fragments: 4 n-tiles x 16 rows; lane supplies k-slice g ----
    // slice0: [xh,xh,xl,xl | yh,yh,yl,yl]   slice1: [zh,zh,zl,zl | nqh,nql,1,1]
    // Groups 2,3 multiply the zero B-fragment, so their content is don't-care
    // (finite) — reuse the g&1 pattern.
    bf16x8 afrag[4];
    const int rowbase = ng * 256 + wave * 64;
#pragma unroll
    for (int nt = 0; nt < 4; ++nt) {
        int row = rowbase + nt * 16 + col;
        float x = tb[row * 3 + 0], y = tb[row * 3 + 1], z = tb[row * 3 + 2];
        float nq = x * x + y * y + z * z;
        __bf16 xh = (__bf16)x, yh = (__bf16)y, zh = (__bf16)z;
        float xl = x - (float)xh, yl = y - (float)yh, zl = z - (float)zh;
        __bf16 nqh = (__bf16)nq; float nql = nq - (float)nqh;
        bf16x8 f0, f1;
        f0[0] = xh; f0[1] = xh; f0[2] = (__bf16)xl; f0[3] = (__bf16)xl;
        f0[4] = yh; f0[5] = yh; f0[6] = (__bf16)yl; f0[7] = (__bf16)yl;
        f1[0] = zh; f1[1] = zh; f1[2] = (__bf16)zl; f1[3] = (__bf16)zl;
        f1[4] = nqh; f1[5] = (__bf16)nql; f1[6] = (__bf16)1.0f; f1[7] = (__bf16)1.0f;
        afrag[nt] = (g & 1) ? f1 : f0;
    }

    __syncthreads();

    // per-lane B pointer: groups 0,1 walk their g-slice; groups 2,3 broadcast
    // the zero fragment (offset step 0).
    const uint4* bptr  = (g < 2) ? &gsl[g][col] : &zfrag;
    const int    bstep = (g < 2) ? 16 : 0;     // uint4 elems per m-tile

    f32x4 cz = {};
    float tmin[4][4];
#pragma unroll
    for (int nt = 0; nt < 4; ++nt)
#pragma unroll
        for (int r = 0; r < 4; ++r) tmin[nt][r] = 3.0e38f;

#pragma unroll 2
    for (int mt2 = 0; mt2 < 16; ++mt2) {
        bf16x8 b0 = __builtin_bit_cast(bf16x8, bptr[bstep * (2 * mt2)]);
        bf16x8 b1 = __builtin_bit_cast(bf16x8, bptr[bstep * (2 * mt2 + 1)]);
        float s0 = 3.0e38f, s1 = 3.0e38f;
#pragma unroll
        for (int nt = 0; nt < 4; ++nt) {
            f32x4 ca = __builtin_amdgcn_mfma_f32_16x16x32_bf16(afrag[nt], b0, cz, 0, 0, 0);
            f32x4 cb = __builtin_amdgcn_mfma_f32_16x16x32_bf16(afrag[nt], b1, cz, 0, 0, 0);
            // template-side: paired fold -> v_min3_f32 (4 per MFMA-pair)
#pragma unroll
            for (int r = 0; r < 4; ++r)
                tmin[nt][r] = fminf(fminf(tmin[nt][r], ca[r]), cb[r]);
            // source-side: 3-ary nests -> 2x v_min3_f32 each
            s0 = fminf(fminf(fminf(fminf(ca[0], ca[1]), ca[2]), ca[3]), s0);
            s1 = fminf(fminf(fminf(fminf(cb[0], cb[1]), cb[2]), cb[3]), s1);
        }
        // fold k-group g <-> g^2 (rows interleave), publish per (wave, g&1)
        s0 = fminf(s0, __shfl_xor(s0, 32));
        s1 = fminf(s1, __shfl_xor(s1, 32));
        if (g < 2) {
            sminW[wave][g][(2 * mt2) * 16 + col]     = fmaxf(s0, 0.0f);
            sminW[wave][g][(2 * mt2 + 1) * 16 + col] = fmaxf(s1, 0.0f);
        }
    }

    // ---- template-side epilogue: col-min via DPP within each 16-lane row ----
#pragma unroll
    for (int nt = 0; nt < 4; ++nt)
#pragma unroll
        for (int r = 0; r < 4; ++r) {
            float v = tmin[nt][r];
            v = dpp_min<0xB1, 0xF>(v);    // quad_perm xor1
            v = dpp_min<0x4E, 0xF>(v);    // quad_perm xor2
            v = dpp_min<0x124, 0xF>(v);   // row_ror:4
            v = dpp_min<0x128, 0xF>(v);   // row_ror:8
            tmin[nt][r] = v;
        }
    if (col == 0) {   // lanes 0,16,32,48: each owns rows g*4+r of its n-tiles
        float* tp = tpart + ((size_t)(b * 32 + ng) * 256) * 16 + mg;
#pragma unroll
        for (int nt = 0; nt < 4; ++nt)
#pragma unroll
            for (int r = 0; r < 4; ++r) {
                int rl = wave * 64 + nt * 16 + g * 4 + r;
                tp[(size_t)rl * 16] = fmaxf(tmin[nt][r], 0.0f);
            }
    }

    __syncthreads();

    // ---- source-side epilogue: fold 4 waves x 2 khalves, write own slots ----
    {
        float v0 = fminf(fminf(fminf(sminW[0][0][t], sminW[0][1][t]),
                               fminf(sminW[1][0][t], sminW[1][1][t])),
                         fminf(fminf(sminW[2][0][t], sminW[2][1][t]),
                               fminf(sminW[3][0][t], sminW[3][1][t])));
        int t2 = t + 256;
        float v1 = fminf(fminf(fminf(sminW[0][0][t2], sminW[0][1][t2]),
                               fminf(sminW[1][0][t2], sminW[1][1][t2])),
                         fminf(fminf(sminW[2][0][t2], sminW[2][1][t2]),
                               fminf(sminW[3][0][t2], sminW[3][1][t2])));
        float* sp = spart + ((size_t)(b * 16 + mg) * 512) * 32 + ng;
        sp[(size_t)t * 32]  = v0;
        sp[(size_t)t2 * 32] = v1;
    }
}

// Pass 2: per point, min over chunk-slots, sqrt, deterministic per-block sums.
// Blocks 0-127: template (16 slots); 128-255: source (32 slots).
__global__ __launch_bounds__(256) void chamfer_reduce_kernel(
    const float* __restrict__ tpart, const float* __restrict__ spart,
    float* __restrict__ partials)
{
    int t = threadIdx.x;
    float m;
    if (blockIdx.x < 128) {
        size_t p = (size_t)blockIdx.x * 256 + t;
        const float4* v4 = (const float4*)(tpart + p * 16);
        float4 a = v4[0], bq = v4[1], cq = v4[2], dq = v4[3];
        float t0 = fminf(fminf(a.x, a.y), a.z);
        float t1 = fminf(fminf(a.w, bq.x), bq.y);
        float t2 = fminf(fminf(bq.z, bq.w), cq.x);
        float t3 = fminf(fminf(cq.y, cq.z), cq.w);
        float t4 = fminf(fminf(dq.x, dq.y), dq.z);
        float u0 = fminf(fminf(t0, t1), dq.w);
        float u1 = fminf(t2, t3);
        m = fminf(fminf(u0, u1), t4);
    } else {
        size_t p = (size_t)(blockIdx.x - 128) * 256 + t;
        const float4* v4 = (const float4*)(spart + p * 32);
        m = 3.0e38f;
#pragma unroll
        for (int k = 0; k < 8; ++k) {
            float4 a = v4[k];
            m = fminf(fminf(fminf(a.x, a.y), a.z), fminf(a.w, m));
        }
    }
    float v = sqrtf(m);

    for (int off = 32; off > 0; off >>= 1) v += __shfl_down(v, off);
    __shared__ float ws[4];
    int wave = t >> 6;
    if ((t & 63) == 0) ws[wave] = v;
    __syncthreads();
    if (t == 0) partials[blockIdx.x] = ws[0] + ws[1] + ws[2] + ws[3];
}

// Pass 3: deterministic final combine.
__global__ void chamfer_final_kernel(const float* __restrict__ partials,
                                     float* __restrict__ out)
{
    int t = threadIdx.x;                 // 256 threads
    float v = partials[t];
    for (int off = 32; off > 0; off >>= 1) v += __shfl_down(v, off);
    __shared__ float ws[4];
    int wave = t >> 6;
    if ((t & 63) == 0) ws[wave] = v;
    __syncthreads();
    if (t == 0) {
        float s0 = ws[0] + ws[1];   // blocks 0-127   = template side
        float s1 = ws[2] + ws[3];   // blocks 128-255 = source side
        out[0] = 0.5f * (s0 + s1) / (float)(BATCH * NPTS);
    }
}

extern "C" void kernel_launch(void* const* d_in, const int* in_sizes, int n_in,
                              void* d_out, int out_size, void* d_ws, size_t ws_size,
                              hipStream_t stream) {
    const float* tpl = (const float*)d_in[0];  // [B, N, 3] fp32
    const float* src = (const float*)d_in[1];  // [B, M, 3] fp32

    // tpart: [32768][16] floats (2 MB), spart: [32768][32] floats (4 MB).
    // Every slot is rewritten each call -> no init needed.
    float* tpart    = (float*)d_ws;
    float* spart    = tpart + (size_t)32768 * 16;
    float* partials = spart + (size_t)32768 * 32;   // 256 floats

    chamfer_mfma_kernel<<<2048, 256, 0, stream>>>(tpl, src, tpart, spart);
    chamfer_reduce_kernel<<<256, 256, 0, stream>>>(tpart, spart, partials);
    chamfer_final_kernel<<<1, 256, 0, stream>>>(partials, (float*)d_out);
}